// Round 3
// baseline (59.770 us; speedup 1.0000x reference)
//
#include <hip/hip_runtime.h>

#define MARGIN 1.0f
#define LAMDA  0.003f
#define EPS_H  1e-9f

// constant term: LAMDA * 4 levels * (B*N=2048) * log(2*pi)
#define E2_CONST (0.003f * 4.0f * 2048.0f * 1.8378770664093453f)

// Per-point gather: computes the 7 per-lane partial values.
// Written as a macro-free inline block via struct to keep loads hoistable.
struct PointVals { float v[7]; };

__device__ __forceinline__ void point_addrs(
    const int* __restrict__ ka, const int* __restrict__ kb,
    const int* __restrict__ na, const int* __restrict__ nb,
    int n, int shift, int S, int plane,
    int& a_pos, int& a_neg_a, int& a_bpos, int& a_neg_b,
    int& a_xm, int& a_xp, int& a_ym, int& a_yp,
    float& sx, float& sy)
{
    const int2 kA = ((const int2*)ka)[n];
    const int2 kB = ((const int2*)kb)[n];
    const int2 nA = ((const int2*)na)[n];
    const int2 nB = ((const int2*)nb)[n];
    const int kax = kA.x >> shift, kay = kA.y >> shift;
    const int kbx = kB.x >> shift, kby = kB.y >> shift;
    const int nax = nA.x >> shift, nay = nA.y >> shift;
    const int nbx = nB.x >> shift, nby = nB.y >> shift;

    a_pos   = plane + kay * S + kax;
    a_neg_a = plane + nay * S + nax;
    a_bpos  = plane + kby * S + kbx;
    a_neg_b = plane + nby * S + nbx;

    const int xm = (kbx > 0)     ? kbx - 1 : 0;
    const int xp = (kbx < S - 1) ? kbx + 1 : S - 1;
    sx = (kbx > 0 && kbx < S - 1) ? 0.5f : 1.0f;
    a_xm = plane + kby * S + xm;
    a_xp = plane + kby * S + xp;

    const int ym = (kby > 0)     ? kby - 1 : 0;
    const int yp = (kby < S - 1) ? kby + 1 : S - 1;
    sy = (kby > 0 && kby < S - 1) ? 0.5f : 1.0f;
    a_ym = plane + ym * S + kbx;
    a_yp = plane + yp * S + kbx;
}

__global__ __launch_bounds__(256) void gn_task_kernel(
    const float* __restrict__ fa0, const float* __restrict__ fa1,
    const float* __restrict__ fa2, const float* __restrict__ fa3,
    const float* __restrict__ fb0, const float* __restrict__ fb1,
    const float* __restrict__ fb2, const float* __restrict__ fb3,
    const int* __restrict__ ka, const int* __restrict__ kb,
    const int* __restrict__ na, const int* __restrict__ nb,
    float* __restrict__ out)
{
    __shared__ float blk[4];
    const int wave = threadIdx.x >> 6;
    const int lane = threadIdx.x & 63;          // lane == channel c (C = 64)
    const int level = wave;                      // one wave per level per block
    const int shift = 3 - level;
    const int S     = 32 << level;

    // two points per wave -> 16 in-flight gathers per lane
    const int n0 = blockIdx.x;                   // 0..1023
    const int n1 = blockIdx.x + 1024;            // 1024..2047
    const int b0 = n0 >> 9;
    const int b1 = n1 >> 9;

    const float* fa; const float* fb;
    switch (level) {
        case 0:  fa = fa0; fb = fb0; break;
        case 1:  fa = fa1; fb = fb1; break;
        case 2:  fa = fa2; fb = fb2; break;
        default: fa = fa3; fb = fb3; break;
    }

    const int plane0 = (b0 * 64 + lane) * (S * S);
    const int plane1 = (b1 * 64 + lane) * (S * S);

    int p0_pos, p0_na, p0_bp, p0_nb, p0_xm, p0_xp, p0_ym, p0_yp;
    int p1_pos, p1_na, p1_bp, p1_nb, p1_xm, p1_xp, p1_ym, p1_yp;
    float sx0, sy0, sx1, sy1;
    point_addrs(ka, kb, na, nb, n0, shift, S, plane0,
                p0_pos, p0_na, p0_bp, p0_nb, p0_xm, p0_xp, p0_ym, p0_yp, sx0, sy0);
    point_addrs(ka, kb, na, nb, n1, shift, S, plane1,
                p1_pos, p1_na, p1_bp, p1_nb, p1_xm, p1_xp, p1_ym, p1_yp, sx1, sy1);

    // Issue all 16 gathers before any math (independent loads; compiler
    // schedules them as one burst with a single waitcnt fence).
    const float va0  = fa[p0_pos];
    const float vna0 = fa[p0_na];
    const float vb0  = fb[p0_bp];
    const float vnb0 = fb[p0_nb];
    const float gxm0 = fb[p0_xm];
    const float gxp0 = fb[p0_xp];
    const float gym0 = fb[p0_ym];
    const float gyp0 = fb[p0_yp];
    const float va1  = fa[p1_pos];
    const float vna1 = fa[p1_na];
    const float vb1  = fb[p1_bp];
    const float vnb1 = fb[p1_nb];
    const float gxm1 = fb[p1_xm];
    const float gxp1 = fb[p1_xp];
    const float gym1 = fb[p1_ym];
    const float gyp1 = fb[p1_yp];

    const float Jx0 = (gxp0 - gxm0) * sx0;
    const float Jy0 = (gyp0 - gym0) * sy0;
    const float Jx1 = (gxp1 - gxm1) * sx1;
    const float Jy1 = (gyp1 - gym1) * sy1;

    const float dpos0 = va0 - vb0;
    const float dneg0 = vna0 - vnb0;
    const float mneg0 = fmaxf(MARGIN - dneg0, 0.0f);
    const float r0    = vb0 - va0;
    const float dpos1 = va1 - vb1;
    const float dneg1 = vna1 - vnb1;
    const float mneg1 = fmaxf(MARGIN - dneg1, 0.0f);
    const float r1    = vb1 - va1;

    float vals[14];
    vals[0]  = dpos0 * dpos0;   vals[7]  = dpos1 * dpos1;
    vals[1]  = mneg0 * mneg0;   vals[8]  = mneg1 * mneg1;
    vals[2]  = Jx0 * Jx0;       vals[9]  = Jx1 * Jx1;
    vals[3]  = Jx0 * Jy0;       vals[10] = Jx1 * Jy1;
    vals[4]  = Jy0 * Jy0;       vals[11] = Jy1 * Jy1;
    vals[5]  = Jx0 * r0;        vals[12] = Jx1 * r1;
    vals[6]  = Jy0 * r0;        vals[13] = Jy1 * r1;

    #pragma unroll
    for (int mask = 32; mask >= 1; mask >>= 1) {
        #pragma unroll
        for (int t = 0; t < 14; ++t)
            vals[t] += __shfl_xor(vals[t], mask, 64);
    }

    if (lane == 0) {
        float o = 0.0f;
        #pragma unroll
        for (int p = 0; p < 2; ++p) {
            const float* v = vals + p * 7;
            const float Hxx = v[2] + EPS_H;
            const float Hxy = v[3];
            const float Hyy = v[4] + EPS_H;
            const float bX  = v[5];
            const float bY  = v[6];
            const float det = Hxx * Hyy - Hxy * Hxy;
            const float e1  = 0.5f * (Hyy * bX * bX - 2.0f * Hxy * bX * bY + Hxx * bY * bY) / det;
            o += (v[0] + v[1]) * (1.0f / 512.0f) + LAMDA * (e1 - 0.5f * logf(det));
        }
        blk[wave] = o;
    }
    __syncthreads();
    if (threadIdx.x == 0) {
        float s = blk[0] + blk[1] + blk[2] + blk[3];
        if (blockIdx.x == 0) s += E2_CONST;
        atomicAdd(out, s);   // device-scope; ~1024 atomics on one line
    }
}

extern "C" void kernel_launch(void* const* d_in, const int* in_sizes, int n_in,
                              void* d_out, int out_size, void* d_ws, size_t ws_size,
                              hipStream_t stream) {
    const float* fa0 = (const float*)d_in[0];
    const float* fa1 = (const float*)d_in[1];
    const float* fa2 = (const float*)d_in[2];
    const float* fa3 = (const float*)d_in[3];
    const float* fb0 = (const float*)d_in[4];
    const float* fb1 = (const float*)d_in[5];
    const float* fb2 = (const float*)d_in[6];
    const float* fb3 = (const float*)d_in[7];
    const int*   ka  = (const int*)d_in[8];
    const int*   kb  = (const int*)d_in[9];
    const int*   na  = (const int*)d_in[10];
    const int*   nb  = (const int*)d_in[11];

    float* out = (float*)d_out;
    hipMemsetAsync(out, 0, sizeof(float), stream);

    gn_task_kernel<<<1024, 256, 0, stream>>>(fa0, fa1, fa2, fa3,
                                             fb0, fb1, fb2, fb3,
                                             ka, kb, na, nb, out);
}

// Round 4
// 55.570 us; speedup vs baseline: 1.0756x; 1.0756x over previous
//
#include <hip/hip_runtime.h>

#define MARGIN 1.0f
#define LAMDA  0.003f
#define EPS_H  1e-9f

// constant term: LAMDA * 4 levels * (B*N=2048) * log(2*pi)
#define E2_CONST (0.003f * 4.0f * 2048.0f * 1.8378770664093453f)

__device__ __forceinline__ float finalize_level(const float* v) {
    const float Hxx = v[2] + EPS_H;
    const float Hxy = v[3];
    const float Hyy = v[4] + EPS_H;
    const float bX  = v[5];
    const float bY  = v[6];
    const float det = Hxx * Hyy - Hxy * Hxy;
    // e1_n = 0.5 * b^T H^{-1} b  (ub == xs so d = H^{-1} b exactly)
    const float e1  = 0.5f * (Hyy * bX * bX - 2.0f * Hxy * bX * bY + Hxx * bY * bY) / det;
    return (v[0] + v[1]) * (1.0f / 512.0f) + LAMDA * (e1 - 0.5f * logf(det));
}

// Classic full-point gather for one level: 8 loads/lane, lane == channel.
__device__ __forceinline__ void gather7(
    const float* __restrict__ fa, const float* __restrict__ fb,
    int2 kA, int2 kB, int2 nA, int2 nB,
    int shift, int S, int plane, float* v)
{
    const int kax = kA.x >> shift, kay = kA.y >> shift;
    const int kbx = kB.x >> shift, kby = kB.y >> shift;
    const int nax = nA.x >> shift, nay = nA.y >> shift;
    const int nbx = nB.x >> shift, nby = nB.y >> shift;

    const float va  = fa[plane + kay * S + kax];
    const float vna = fa[plane + nay * S + nax];
    const float vb  = fb[plane + kby * S + kbx];
    const float vnb = fb[plane + nby * S + nbx];

    const int   xm = (kbx > 0)     ? kbx - 1 : 0;
    const int   xp = (kbx < S - 1) ? kbx + 1 : S - 1;
    const float sx = (kbx > 0 && kbx < S - 1) ? 0.5f : 1.0f;
    const int   ym = (kby > 0)     ? kby - 1 : 0;
    const int   yp = (kby < S - 1) ? kby + 1 : S - 1;
    const float sy = (kby > 0 && kby < S - 1) ? 0.5f : 1.0f;
    const float Jx = (fb[plane + kby * S + xp] - fb[plane + kby * S + xm]) * sx;
    const float Jy = (fb[plane + yp * S + kbx] - fb[plane + ym * S + kbx]) * sy;

    const float dpos = va - vb;
    const float dneg = vna - vnb;
    const float mneg = fmaxf(MARGIN - dneg, 0.0f);
    const float r    = vb - va;

    v[0] = dpos * dpos;
    v[1] = mneg * mneg;
    v[2] = Jx * Jx;
    v[3] = Jx * Jy;
    v[4] = Jy * Jy;
    v[5] = Jx * r;
    v[6] = Jy * r;
}

__global__ __launch_bounds__(256) void gn_task_kernel(
    const float* __restrict__ fa0, const float* __restrict__ fa1,
    const float* __restrict__ fa2, const float* __restrict__ fa3,
    const float* __restrict__ fb0, const float* __restrict__ fb1,
    const float* __restrict__ fb2, const float* __restrict__ fb3,
    const int* __restrict__ ka, const int* __restrict__ kb,
    const int* __restrict__ na, const int* __restrict__ nb,
    float* __restrict__ out)
{
    __shared__ float l3sums[2][7];
    __shared__ float wloss[2];

    const int wave = threadIdx.x >> 6;
    const int lane = threadIdx.x & 63;
    const int n    = blockIdx.x;          // one point per block (R1 locality)
    const int b    = n >> 9;              // N = 512

    const int2 kA = ((const int2*)ka)[n];
    const int2 kB = ((const int2*)kb)[n];
    const int2 nA = ((const int2*)na)[n];
    const int2 nB = ((const int2*)nb)[n];

    if (wave < 2) {
        // ---- level 3 (256x256, shift 0), split across waves 0/1 by channel,
        // and within a wave by lane role: 4 loads per lane instead of 8.
        const int role = lane >> 5;                 // 0: values, 1: gradient taps
        const int c    = (wave << 5) + (lane & 31); // channel 0..63
        const int plane = (b * 64 + c) * (256 * 256);

        // role-0 addresses (fa3/fa3/fb3/fb3)
        const int a0v = plane + kA.y * 256 + kA.x;  // va
        const int a1v = plane + nA.y * 256 + nA.x;  // vna
        const int a2v = plane + kB.y * 256 + kB.x;  // vb
        const int a3v = plane + nB.y * 256 + nB.x;  // vnb

        // role-1 addresses (all fb3): gradient taps at kb
        const int kbx = kB.x, kby = kB.y;
        const int xm = (kbx > 0)   ? kbx - 1 : 0;
        const int xp = (kbx < 255) ? kbx + 1 : 255;
        const float sx = (kbx > 0 && kbx < 255) ? 0.5f : 1.0f;
        const int ym = (kby > 0)   ? kby - 1 : 0;
        const int yp = (kby < 255) ? kby + 1 : 255;
        const float sy = (kby > 0 && kby < 255) ? 0.5f : 1.0f;
        const int a0g = plane + kby * 256 + xm;
        const int a1g = plane + kby * 256 + xp;
        const int a2g = plane + ym * 256 + kbx;
        const int a3g = plane + yp * 256 + kbx;

        const float* p0 = role ? fb3 : fa3;
        const float* p1 = role ? fb3 : fa3;
        const int a0 = role ? a0g : a0v;
        const int a1 = role ? a1g : a1v;
        const int a2 = role ? a2g : a2v;
        const int a3 = role ? a3g : a3v;

        const float L0 = p0[a0];
        const float L1 = p1[a1];
        const float L2 = fb3[a2];
        const float L3 = fb3[a3];

        // role0: L0=va, L1=vna, L2=vb, L3=vnb. role1: L0=gxm, L1=gxp, L2=gym, L3=gyp.
        const float r    = L2 - L0;                 // valid on role0 lanes
        const float rsw  = __shfl_xor(r, 32, 64);   // bring r to role1 lanes
        const float Jx   = (L1 - L0) * sx;          // valid on role1 lanes
        const float Jy   = (L3 - L2) * sy;
        const float dpos = L0 - L2;
        const float dneg = L1 - L3;
        const float mneg = fmaxf(MARGIN - dneg, 0.0f);

        float v[7];
        v[0] = role ? 0.0f : dpos * dpos;
        v[1] = role ? 0.0f : mneg * mneg;
        v[2] = role ? Jx * Jx  : 0.0f;
        v[3] = role ? Jx * Jy  : 0.0f;
        v[4] = role ? Jy * Jy  : 0.0f;
        v[5] = role ? Jx * rsw : 0.0f;
        v[6] = role ? Jy * rsw : 0.0f;

        #pragma unroll
        for (int mask = 32; mask >= 1; mask >>= 1)
            #pragma unroll
            for (int t = 0; t < 7; ++t)
                v[t] += __shfl_xor(v[t], mask, 64);

        if (lane == 0)
            #pragma unroll
            for (int t = 0; t < 7; ++t) l3sums[wave][t] = v[t];
    } else if (wave == 2) {
        // ---- level 2 (128x128, shift 1): classic 8-load path
        float v[7];
        const int plane = (b * 64 + lane) * (128 * 128);
        gather7(fa2, fb2, kA, kB, nA, nB, 1, 128, plane, v);
        #pragma unroll
        for (int mask = 32; mask >= 1; mask >>= 1)
            #pragma unroll
            for (int t = 0; t < 7; ++t)
                v[t] += __shfl_xor(v[t], mask, 64);
        if (lane == 0) wloss[0] = finalize_level(v);
    } else {
        // ---- levels 1 (64x64, shift 2) + 0 (32x32, shift 3): 16 cheap loads
        float v[14];
        const int plane1 = (b * 64 + lane) * (64 * 64);
        const int plane0 = (b * 64 + lane) * (32 * 32);
        gather7(fa1, fb1, kA, kB, nA, nB, 2, 64, plane1, v);
        gather7(fa0, fb0, kA, kB, nA, nB, 3, 32, plane0, v + 7);
        #pragma unroll
        for (int mask = 32; mask >= 1; mask >>= 1)
            #pragma unroll
            for (int t = 0; t < 14; ++t)
                v[t] += __shfl_xor(v[t], mask, 64);
        if (lane == 0) wloss[1] = finalize_level(v) + finalize_level(v + 7);
    }

    __syncthreads();
    if (threadIdx.x == 0) {
        float v3[7];
        #pragma unroll
        for (int t = 0; t < 7; ++t) v3[t] = l3sums[0][t] + l3sums[1][t];
        float s = finalize_level(v3) + wloss[0] + wloss[1];
        if (blockIdx.x == 0) s += E2_CONST;
        atomicAdd(out, s);
    }
}

extern "C" void kernel_launch(void* const* d_in, const int* in_sizes, int n_in,
                              void* d_out, int out_size, void* d_ws, size_t ws_size,
                              hipStream_t stream) {
    const float* fa0 = (const float*)d_in[0];
    const float* fa1 = (const float*)d_in[1];
    const float* fa2 = (const float*)d_in[2];
    const float* fa3 = (const float*)d_in[3];
    const float* fb0 = (const float*)d_in[4];
    const float* fb1 = (const float*)d_in[5];
    const float* fb2 = (const float*)d_in[6];
    const float* fb3 = (const float*)d_in[7];
    const int*   ka  = (const int*)d_in[8];
    const int*   kb  = (const int*)d_in[9];
    const int*   na  = (const int*)d_in[10];
    const int*   nb  = (const int*)d_in[11];

    float* out = (float*)d_out;
    hipMemsetAsync(out, 0, sizeof(float), stream);

    gn_task_kernel<<<2048, 256, 0, stream>>>(fa0, fa1, fa2, fa3,
                                             fb0, fb1, fb2, fb3,
                                             ka, kb, na, nb, out);
}

// Round 5
// 52.607 us; speedup vs baseline: 1.1362x; 1.0563x over previous
//
#include <hip/hip_runtime.h>

#define MARGIN 1.0f
#define LAMDA  0.003f
#define EPS_H  1e-9f

// constant term: LAMDA * 4 levels * (B*N=2048) * log(2*pi)
#define E2_CONST (0.003f * 4.0f * 2048.0f * 1.8378770664093453f)

template <bool NT>
__device__ __forceinline__ float ldf(const float* __restrict__ p) {
    if (NT) return __builtin_nontemporal_load(p);
    return *p;
}

__device__ __forceinline__ float finalize_level(const float* v) {
    const float Hxx = v[2] + EPS_H;
    const float Hxy = v[3];
    const float Hyy = v[4] + EPS_H;
    const float bX  = v[5];
    const float bY  = v[6];
    const float det = Hxx * Hyy - Hxy * Hxy;
    // e1_n = 0.5 * b^T H^{-1} b  (ub == xs so d = H^{-1} b exactly)
    const float e1  = 0.5f * (Hyy * bX * bX - 2.0f * Hxy * bX * bY + Hxx * bY * bY) / det;
    return (v[0] + v[1]) * (1.0f / 512.0f) + LAMDA * (e1 - 0.5f * logf(det));
}

// Full-point gather for one level: 8 loads/lane, lane == channel.
// NT: use non-temporal loads (level 3 — single-use lines, keep them out of L3).
template <bool NT>
__device__ __forceinline__ void gather7(
    const float* __restrict__ fa, const float* __restrict__ fb,
    int2 kA, int2 kB, int2 nA, int2 nB,
    int shift, int S, int plane, float* v)
{
    const int kax = kA.x >> shift, kay = kA.y >> shift;
    const int kbx = kB.x >> shift, kby = kB.y >> shift;
    const int nax = nA.x >> shift, nay = nA.y >> shift;
    const int nbx = nB.x >> shift, nby = nB.y >> shift;

    const int   xm = (kbx > 0)     ? kbx - 1 : 0;
    const int   xp = (kbx < S - 1) ? kbx + 1 : S - 1;
    const float sx = (kbx > 0 && kbx < S - 1) ? 0.5f : 1.0f;
    const int   ym = (kby > 0)     ? kby - 1 : 0;
    const int   yp = (kby < S - 1) ? kby + 1 : S - 1;
    const float sy = (kby > 0 && kby < S - 1) ? 0.5f : 1.0f;

    // 8 independent loads issued as one burst
    const float va  = ldf<NT>(fa + plane + kay * S + kax);
    const float vna = ldf<NT>(fa + plane + nay * S + nax);
    const float vb  = ldf<NT>(fb + plane + kby * S + kbx);
    const float vnb = ldf<NT>(fb + plane + nby * S + nbx);
    const float gxm = ldf<NT>(fb + plane + kby * S + xm);
    const float gxp = ldf<NT>(fb + plane + kby * S + xp);
    const float gym = ldf<NT>(fb + plane + ym * S + kbx);
    const float gyp = ldf<NT>(fb + plane + yp * S + kbx);

    const float Jx = (gxp - gxm) * sx;
    const float Jy = (gyp - gym) * sy;

    const float dpos = va - vb;
    const float dneg = vna - vnb;
    const float mneg = fmaxf(MARGIN - dneg, 0.0f);
    const float r    = vb - va;

    v[0] = dpos * dpos;
    v[1] = mneg * mneg;
    v[2] = Jx * Jx;
    v[3] = Jx * Jy;
    v[4] = Jy * Jy;
    v[5] = Jx * r;
    v[6] = Jy * r;
}

__global__ __launch_bounds__(256) void gn_task_kernel(
    const float* __restrict__ fa0, const float* __restrict__ fa1,
    const float* __restrict__ fa2, const float* __restrict__ fa3,
    const float* __restrict__ fb0, const float* __restrict__ fb1,
    const float* __restrict__ fb2, const float* __restrict__ fb3,
    const int* __restrict__ ka, const int* __restrict__ kb,
    const int* __restrict__ na, const int* __restrict__ nb,
    float* __restrict__ out)
{
    __shared__ float wloss[4];

    const int wave  = threadIdx.x >> 6;
    const int lane  = threadIdx.x & 63;      // lane == channel c (C = 64)
    const int level = wave;                   // R1 shape: one wave per level
    const int n     = blockIdx.x;             // one point per block
    const int b     = n >> 9;                 // N = 512
    const int shift = 3 - level;
    const int S     = 32 << level;

    const int2 kA = ((const int2*)ka)[n];
    const int2 kB = ((const int2*)kb)[n];
    const int2 nA = ((const int2*)na)[n];
    const int2 nB = ((const int2*)nb)[n];

    const int plane = (b * 64 + lane) * (S * S);

    float v[7];
    if (level == 3) {
        // level-3 lines are single-use: non-temporal, don't thrash L3
        gather7<true>(fa3, fb3, kA, kB, nA, nB, 0, 256, plane, v);
    } else if (level == 2) {
        gather7<false>(fa2, fb2, kA, kB, nA, nB, 1, 128, plane, v);
    } else if (level == 1) {
        gather7<false>(fa1, fb1, kA, kB, nA, nB, 2, 64, plane, v);
    } else {
        gather7<false>(fa0, fb0, kA, kB, nA, nB, 3, 32, plane, v);
    }

    // wave-wide (64-lane) butterfly reduction
    #pragma unroll
    for (int mask = 32; mask >= 1; mask >>= 1)
        #pragma unroll
        for (int t = 0; t < 7; ++t)
            v[t] += __shfl_xor(v[t], mask, 64);

    if (lane == 0)
        wloss[wave] = finalize_level(v);

    __syncthreads();
    if (threadIdx.x == 0) {
        float s = wloss[0] + wloss[1] + wloss[2] + wloss[3];
        if (blockIdx.x == 0) s += E2_CONST;
        atomicAdd(out, s);   // device-scope, ~2048 atomics on one line
    }
}

extern "C" void kernel_launch(void* const* d_in, const int* in_sizes, int n_in,
                              void* d_out, int out_size, void* d_ws, size_t ws_size,
                              hipStream_t stream) {
    const float* fa0 = (const float*)d_in[0];
    const float* fa1 = (const float*)d_in[1];
    const float* fa2 = (const float*)d_in[2];
    const float* fa3 = (const float*)d_in[3];
    const float* fb0 = (const float*)d_in[4];
    const float* fb1 = (const float*)d_in[5];
    const float* fb2 = (const float*)d_in[6];
    const float* fb3 = (const float*)d_in[7];
    const int*   ka  = (const int*)d_in[8];
    const int*   kb  = (const int*)d_in[9];
    const int*   na  = (const int*)d_in[10];
    const int*   nb  = (const int*)d_in[11];

    float* out = (float*)d_out;
    hipMemsetAsync(out, 0, sizeof(float), stream);

    gn_task_kernel<<<2048, 256, 0, stream>>>(fa0, fa1, fa2, fa3,
                                             fb0, fb1, fb2, fb3,
                                             ka, kb, na, nb, out);
}